// Round 17
// baseline (151.107 us; speedup 1.0000x reference)
//
#include <hip/hip_runtime.h>
#include <math.h>

// StickBreakingVAE forward, all-bf16 MFMA, 8-wave blocks, XCD swizzle.
// r17: 2-phase LDS double-buffer in mfma_gemm (T3-minimum recipe; one barrier
// per K-tile, loads for t+1 in flight under compute of t). 8-wave blocks keep
// 16 waves/CU at 64KB LDS (r5's 4-wave dbuf failure was occupancy collapse).
// Kernels: prep_cast, GEMM1, mid_fused, GEMM5. B=32768, D=784, H=500, K=50.

typedef __bf16 bf16x8 __attribute__((ext_vector_type(8)));
typedef float f32x4 __attribute__((ext_vector_type(4)));

#define BATCH 32768
#define BM 128
#define BN 128
#define BK 64
#define NTHR 512

__device__ __forceinline__ unsigned short bf16_bits(float f) {
    __bf16 b = (__bf16)f;
    return __builtin_bit_cast(unsigned short, b);
}

__device__ __forceinline__ float f32_from_bf16(unsigned short s) {
    unsigned int ui = ((unsigned int)s) << 16;
    return __builtin_bit_cast(float, ui);
}

__device__ __forceinline__ void gll16(const void* src, void* ldsdst) {
    __builtin_amdgcn_global_load_lds(
        (const __attribute__((address_space(1))) unsigned int*)src,
        (__attribute__((address_space(3))) unsigned int*)ldsdst,
        16, 0, 0);
}

// chunked bijective XCD swizzle (T1, m204)
__device__ __forceinline__ int xcd_swz(int orig, int nwg) {
    int q = nwg >> 3, r8 = nwg & 7;
    int xcd = orig & 7;
    int chunkbase = (xcd < r8) ? xcd * (q + 1) : r8 * (q + 1) + (xcd - r8) * q;
    return chunkbase + (orig >> 3);
}

// MODE 0: relu -> bf16 C [ldc]; MODE 2: sigmoid -> f32 C [B,Nreal] masked.
template<int MODE>
__global__ __launch_bounds__(NTHR, 4) void mfma_gemm(
    const unsigned short* __restrict__ A,   // [M][lda] bf16 (zero-padded)
    const unsigned short* __restrict__ Bt,  // [Npad][Kpad] bf16 (zero-padded)
    const float* __restrict__ bias,         // [Npad]
    void* __restrict__ Cv,
    int Kpad, int lda, int ldc, int Nreal, int nbx)
{
    __shared__ unsigned short As[2][BM * BK];   // double-buffered, 64KB total
    __shared__ unsigned short Bs[2][BN * BK];

    const int wgid = xcd_swz(blockIdx.x, gridDim.x);
    const int bn = wgid % nbx;
    const size_t block_m = (size_t)(wgid / nbx) * BM;
    const int block_n = bn * BN;

    const int tid = threadIdx.x;
    const int l = tid & 63;
    const int wid = tid >> 6;
    const int wr = wid >> 2, wc = wid & 3;   // wave tile 64x32
    const int lr = l & 15;
    const int kh = l >> 4;

    f32x4 acc[4][2] = {};

    auto stage = [&](int k0, int buf) {
        #pragma unroll
        for (int i = 0; i < 2; ++i) {
            int chunk = wid * 2 + i;          // 16 chunks x 64 granules(16B)
            int gid = chunk * 64 + l;
            int r = gid >> 3;                 // tile row 0..127
            int kgs = (gid & 7) ^ (r & 7);    // pre-swizzled source granule
            gll16(Bt + (size_t)(block_n + r) * Kpad + k0 + kgs * 8,
                  &Bs[buf][chunk * 512]);
            gll16(A + (block_m + r) * (size_t)lda + k0 + kgs * 8,
                  &As[buf][chunk * 512]);
        }
    };

    auto compute = [&](int buf) {
        #pragma unroll
        for (int s = 0; s < 2; ++s) {
            bf16x8 af[4], bf[2];
            #pragma unroll
            for (int mi = 0; mi < 4; ++mi) {
                int row = wr * 64 + mi * 16 + lr;
                int g = (s * 4 + kh) ^ (row & 7);
                af[mi] = *(const bf16x8*)(&As[buf][row * 64 + g * 8]);
            }
            #pragma unroll
            for (int ni = 0; ni < 2; ++ni) {
                int row = wc * 32 + ni * 16 + lr;
                int g = (s * 4 + kh) ^ (row & 7);
                bf[ni] = *(const bf16x8*)(&Bs[buf][row * 64 + g * 8]);
            }
            #pragma unroll
            for (int mi = 0; mi < 4; ++mi)
                #pragma unroll
                for (int ni = 0; ni < 2; ++ni)
                    acc[mi][ni] = __builtin_amdgcn_mfma_f32_16x16x32_bf16(
                        af[mi], bf[ni], acc[mi][ni], 0, 0, 0);
        }
    };

    const int nt = Kpad / BK;
    stage(0, 0);
    __syncthreads();                          // tile 0 landed
    for (int t = 0; t < nt; ++t) {
        if (t + 1 < nt) stage((t + 1) * BK, (t + 1) & 1);   // prefetch next
        compute(t & 1);
        __syncthreads();   // my glls drained + all waves done reading buf t&1
    }

    const int rg = (l >> 4) * 4;
    #pragma unroll
    for (int mi = 0; mi < 4; ++mi) {
        #pragma unroll
        for (int ni = 0; ni < 2; ++ni) {
            int gn = block_n + wc * 32 + ni * 16 + lr;
            float bs = bias[gn];
            #pragma unroll
            for (int j = 0; j < 4; ++j) {
                long gm = block_m + wr * 64 + mi * 16 + rg + j;
                float z = acc[mi][ni][j] + bs;
                if (MODE == 0) {
                    z = fmaxf(z, 0.f);
                    ((unsigned short*)Cv)[gm * ldc + gn] = bf16_bits(z);
                } else {
                    if (gn < Nreal) {
                        z = __fdividef(1.f, 1.f + __expf(-z));
                        ((float*)Cv)[gm * Nreal + gn] = z;
                    }
                }
            }
        }
    }
}

// Fused GEMM2/3 + softplus + sample + GEMM4. Grid 256 x 512thr, 80KB LDS.
__global__ __launch_bounds__(NTHR, 2) void mid_fused(
    const unsigned short* __restrict__ h,      // [B][512] bf16
    const unsigned short* __restrict__ wab,    // [128][512] bf16
    const float* __restrict__ biasab,          // [128]
    const float* __restrict__ u,               // [B][50] f32
    const unsigned short* __restrict__ dw1b,   // [512][64] bf16
    const float* __restrict__ biasd1,          // [512]
    float* __restrict__ outAB,                 // alpha base (d_out + B*784)
    unsigned short* __restrict__ hdb)          // [B][512] bf16 (aliases h)
{
    __shared__ __align__(16) unsigned char smem[81920];   // 80 KB -> 2 blocks/CU
    unsigned short* abh = (unsigned short*)smem;          // [2][128][64] bf16, 32KB
    unsigned short* Pi  = (unsigned short*)(smem + 32768);       // [128][64], 16KB
    unsigned short* Wd  = (unsigned short*)(smem + 49152);       // [2][128][64], 32KB
    unsigned short* As  = (unsigned short*)(smem + 49152);       // P1 alias of Wd
    unsigned short* Bs  = (unsigned short*)(smem + 65536);

    const int tid = threadIdx.x;
    const int l = tid & 63;
    const int wid = tid >> 6;
    const int wr = wid >> 2, wc = wid & 3;
    const int lr = l & 15;
    const int kh = l >> 4;
    const int rg = (l >> 4) * 4;

    const int wgid = xcd_swz(blockIdx.x, gridDim.x);
    const size_t block_m = (size_t)wgid * 128;

    // ---- P1: alpha/beta pre-act = h @ wab, K=512 ----
    {
        f32x4 acc[4][2] = {};
        for (int k0 = 0; k0 < 512; k0 += BK) {
            #pragma unroll
            for (int i = 0; i < 2; ++i) {
                int chunk = wid * 2 + i;
                int gid = chunk * 64 + l;
                int r = gid >> 3;
                int kgs = (gid & 7) ^ (r & 7);
                gll16(wab + (size_t)r * 512 + k0 + kgs * 8, Bs + chunk * 512);
            }
            #pragma unroll
            for (int i = 0; i < 2; ++i) {
                int chunk = wid * 2 + i;
                int gid = chunk * 64 + l;
                int r = gid >> 3;
                int kgs = (gid & 7) ^ (r & 7);
                gll16(h + (block_m + r) * 512 + k0 + kgs * 8, As + chunk * 512);
            }
            __syncthreads();
            #pragma unroll
            for (int s = 0; s < 2; ++s) {
                bf16x8 af[4], bf[2];
                #pragma unroll
                for (int mi = 0; mi < 4; ++mi) {
                    int row = wr * 64 + mi * 16 + lr;
                    int g = (s * 4 + kh) ^ (row & 7);
                    af[mi] = *(const bf16x8*)(As + row * 64 + g * 8);
                }
                #pragma unroll
                for (int ni = 0; ni < 2; ++ni) {
                    int row = wc * 32 + ni * 16 + lr;
                    int g = (s * 4 + kh) ^ (row & 7);
                    bf[ni] = *(const bf16x8*)(Bs + row * 64 + g * 8);
                }
                #pragma unroll
                for (int mi = 0; mi < 4; ++mi)
                    #pragma unroll
                    for (int ni = 0; ni < 2; ++ni)
                        acc[mi][ni] = __builtin_amdgcn_mfma_f32_16x16x32_bf16(
                            af[mi], bf[ni], acc[mi][ni], 0, 0, 0);
            }
            __syncthreads();   // last iter: As/Bs reads done -> Wd region reusable
        }

        // ---- stage dec_w1 tile 0 early (lands during P2/P3) ----
        #pragma unroll
        for (int i = 0; i < 2; ++i) {
            int chunk = wid * 2 + i;
            int gid = chunk * 64 + l;
            int r = gid >> 3;
            int kgs = (gid & 7) ^ (r & 7);
            gll16(dw1b + (size_t)r * 64 + kgs * 8, Wd + chunk * 512);
        }

        // ---- P2: softplus -> d_out (f32 exact) + LDS ab (bf16) ----
        #pragma unroll
        for (int mi = 0; mi < 4; ++mi) {
            #pragma unroll
            for (int ni = 0; ni < 2; ++ni) {
                int gn = wc * 32 + ni * 16 + lr;       // 0..127
                float bs = biasab[gn];
                #pragma unroll
                for (int j = 0; j < 4; ++j) {
                    int lm = wr * 64 + mi * 16 + rg + j;
                    long gm = block_m + lm;
                    float z = acc[mi][ni][j] + bs;
                    z = (z > 0.f) ? z + __logf(1.f + __expf(-z))
                                  : __logf(1.f + __expf(z));
                    if (gn < 50) {
                        outAB[gm * 50 + gn] = z;
                        abh[lm * 64 + gn] = bf16_bits(z);               // alpha
                    } else if (gn < 100) {
                        outAB[(size_t)BATCH * 50 + gm * 50 + (gn - 50)] = z;
                        abh[8192 + lm * 64 + (gn - 50)] = bf16_bits(z); // beta
                    }
                }
            }
        }
    }

    // ---- P3: sample. u hoisted to regs BEFORE barrier; a,b from LDS bf16 ----
    float ur[16];
    #pragma unroll
    for (int rr = 0; rr < 16; ++rr) {
        size_t grow = block_m + wid * 16 + rr;
        ur[rr] = (l < 50) ? u[grow * 50 + l] : 0.5f;
    }
    __syncthreads();   // abh visible (drains vmcnt too; Wd tile0 landed)

    #pragma unroll
    for (int rr = 0; rr < 16; ++rr) {
        int row = wid * 16 + rr;
        float v = 0.f, w = 1.f;
        if (l < 50) {
            float a = f32_from_bf16(abh[row * 64 + l]);
            float b = f32_from_bf16(abh[8192 + row * 64 + l]);
            float t = exp2f(__fdividef(log2f(ur[rr]), b));      // u^(1/beta)
            v = exp2f(__fdividef(log2f(1.f - t), a));           // (1-t)^(1/alpha)
            w = 1.f - v;
        }
        float p = w;
        #pragma unroll
        for (int off = 1; off < 64; off <<= 1) {
            float t2 = __shfl_up(p, off, 64);
            if (l >= off) p *= t2;
        }
        float ex = __shfl_up(p, 1, 64);
        if (l == 0) ex = 1.f;
        float pi = (l < 50) ? v * ex : 0.f;
        Pi[row * 64 + (((l >> 3) ^ (row & 7)) << 3) + (l & 7)] = bf16_bits(pi);
    }
    __syncthreads();   // Pi ready

    // ---- P4: hd = relu(pi @ dec_w1 + b), 4 n-tiles, Wd dbuf ----
    for (int j = 0; j < 4; ++j) {
        if (j < 3) {
            int buf = (j + 1) & 1;
            #pragma unroll
            for (int i = 0; i < 2; ++i) {
                int chunk = wid * 2 + i;
                int gid = chunk * 64 + l;
                int r = gid >> 3;
                int kgs = (gid & 7) ^ (r & 7);
                gll16(dw1b + (size_t)((j + 1) * 128 + r) * 64 + kgs * 8,
                      Wd + buf * 8192 + chunk * 512);
            }
        }
        f32x4 acc[4][2] = {};
        const unsigned short* W = Wd + (j & 1) * 8192;
        #pragma unroll
        for (int s = 0; s < 2; ++s) {
            bf16x8 af[4], bf[2];
            #pragma unroll
            for (int mi = 0; mi < 4; ++mi) {
                int row = wr * 64 + mi * 16 + lr;
                int g = (s * 4 + kh) ^ (row & 7);
                af[mi] = *(const bf16x8*)(Pi + row * 64 + g * 8);
            }
            #pragma unroll
            for (int ni = 0; ni < 2; ++ni) {
                int row = wc * 32 + ni * 16 + lr;
                int g = (s * 4 + kh) ^ (row & 7);
                bf[ni] = *(const bf16x8*)(W + row * 64 + g * 8);
            }
            #pragma unroll
            for (int mi = 0; mi < 4; ++mi)
                #pragma unroll
                for (int ni = 0; ni < 2; ++ni)
                    acc[mi][ni] = __builtin_amdgcn_mfma_f32_16x16x32_bf16(
                        af[mi], bf[ni], acc[mi][ni], 0, 0, 0);
        }
        #pragma unroll
        for (int mi = 0; mi < 4; ++mi) {
            #pragma unroll
            for (int ni = 0; ni < 2; ++ni) {
                int gn = j * 128 + wc * 32 + ni * 16 + lr;
                float bs = biasd1[gn];
                #pragma unroll
                for (int jj = 0; jj < 4; ++jj) {
                    long gm = block_m + wr * 64 + mi * 16 + rg + jj;
                    float z = fmaxf(acc[mi][ni][jj] + bs, 0.f);
                    hdb[gm * 512 + gn] = bf16_bits(z);
                }
            }
        }
        __syncthreads();   // Wd[j&1] reads done + next tile landed
    }
}

// Merged weight preps + cast_x. blockIdx ranges:
//  [0,1664): w1b  [1664,1920): wab  [1920,2048): dw1b  [2048,3840): dw2b
//  [3840, 3840+13312): cast_x granule pass
__global__ __launch_bounds__(256) void prep_cast(
    const float* __restrict__ x, unsigned short* __restrict__ xb,
    const float* __restrict__ enc_w1, const float* __restrict__ enc_b1,
    const float* __restrict__ Wa, const float* __restrict__ ba,
    const float* __restrict__ Wb, const float* __restrict__ bb,
    const float* __restrict__ dec_w1, const float* __restrict__ dec_b1,
    const float* __restrict__ dec_w2, const float* __restrict__ dec_b2,
    unsigned short* __restrict__ w1b, float* __restrict__ bias1,
    unsigned short* __restrict__ wab, float* __restrict__ biasab,
    unsigned short* __restrict__ dw1b, float* __restrict__ biasd1,
    unsigned short* __restrict__ dw2b, float* __restrict__ biasd2)
{
    int bid = blockIdx.x;
    int t = threadIdx.x;
    if (bid >= 3840) {                   // cast_x: x f32 -> xb bf16 [B][832]
        int gid = (bid - 3840) * 256 + t;
        int r = gid / 104;
        int c = gid - r * 104;
        union { __bf16 b[8]; uint4 u4; } pk;
        if (c < 98) {
            const float4* p = (const float4*)(x + (size_t)r * 784 + c * 8);
            float4 f0 = p[0], f1 = p[1];
            pk.b[0] = (__bf16)f0.x; pk.b[1] = (__bf16)f0.y;
            pk.b[2] = (__bf16)f0.z; pk.b[3] = (__bf16)f0.w;
            pk.b[4] = (__bf16)f1.x; pk.b[5] = (__bf16)f1.y;
            pk.b[6] = (__bf16)f1.z; pk.b[7] = (__bf16)f1.w;
        } else {
            pk.u4 = make_uint4(0, 0, 0, 0);
        }
        *(uint4*)(xb + (size_t)r * 832 + c * 8) = pk.u4;
    } else if (bid < 1664) {             // w1b
        int idx = bid * 256 + t;
        int n = idx / 832, k = idx - n * 832;
        float v = (n < 500 && k < 784) ? enc_w1[(size_t)k * 500 + n] : 0.f;
        w1b[idx] = bf16_bits(v);
        if (k == 0) bias1[n] = (n < 500) ? enc_b1[n] : 0.f;
    } else if (bid < 1920) {             // wab
        int idx = (bid - 1664) * 256 + t;
        int n = idx >> 9, k = idx & 511;
        float v = 0.f;
        if (k < 500) {
            if (n < 50)       v = Wa[(size_t)k * 50 + n];
            else if (n < 100) v = Wb[(size_t)k * 50 + (n - 50)];
        }
        wab[idx] = bf16_bits(v);
        if (k == 0) biasab[n] = (n < 50) ? ba[n] : ((n < 100) ? bb[n - 50] : 0.f);
    } else if (bid < 2048) {             // dw1b
        int idx = (bid - 1920) * 256 + t;
        int n = idx >> 6, k = idx & 63;
        float v = (n < 500 && k < 50) ? dec_w1[(size_t)k * 500 + n] : 0.f;
        dw1b[idx] = bf16_bits(v);
        if (k == 0) biasd1[n] = (n < 500) ? dec_b1[n] : 0.f;
    } else {                             // dw2b
        int idx = (bid - 2048) * 256 + t;
        int n = idx >> 9, k = idx & 511;
        float v = (n < 784 && k < 500) ? dec_w2[(size_t)k * 784 + n] : 0.f;
        dw2b[idx] = bf16_bits(v);
        if (k == 0) biasd2[n] = (n < 784) ? dec_b2[n] : 0.f;
    }
}

extern "C" void kernel_launch(void* const* d_in, const int* in_sizes, int n_in,
                              void* d_out, int out_size, void* d_ws, size_t ws_size,
                              hipStream_t stream) {
    const float* x       = (const float*)d_in[0];
    const float* u       = (const float*)d_in[1];
    const float* enc_w1  = (const float*)d_in[2];
    const float* enc_b1  = (const float*)d_in[3];
    const float* w_alpha = (const float*)d_in[4];
    const float* b_alpha = (const float*)d_in[5];
    const float* w_beta  = (const float*)d_in[6];
    const float* b_beta  = (const float*)d_in[7];
    const float* dec_w1  = (const float*)d_in[8];
    const float* dec_b1  = (const float*)d_in[9];
    const float* dec_w2  = (const float*)d_in[10];
    const float* dec_b2  = (const float*)d_in[11];

    const int D = 784;

    float* out   = (float*)d_out;
    float* recon = out;                              // [B,784] f32
    float* alpha = out + (size_t)BATCH * D;          // [B,50]; beta at +B*50

    unsigned short* xb = (unsigned short*)d_out;     // [B][832] bf16, dead til GEMM5

    char* ws = (char*)d_ws;
    unsigned short* w1b  = (unsigned short*)(ws);             // 512*832*2
    unsigned short* wab  = (unsigned short*)(ws + 851968);    // 128*512*2
    unsigned short* dw1b = (unsigned short*)(ws + 983040);    // 512*64*2
    unsigned short* dw2b = (unsigned short*)(ws + 1048576);   // 896*512*2
    float* bias1  = (float*)(ws + 1966080);
    float* biasab = (float*)(ws + 1968128);
    float* biasd1 = (float*)(ws + 1970688);
    float* biasd2 = (float*)(ws + 1972736);
    unsigned short* h    = (unsigned short*)(ws + 2097152);   // [B][512] bf16
    unsigned short* hdb  = h;                                  // per-block phase-safe alias

    // ---- prep + cast (one launch) ----
    prep_cast<<<dim3(3840 + BATCH * 104 / 256), 256, 0, stream>>>(
        x, xb, enc_w1, enc_b1, w_alpha, b_alpha, w_beta, b_beta,
        dec_w1, dec_b1, dec_w2, dec_b2,
        w1b, bias1, wab, biasab, dw1b, biasd1, dw2b, biasd2);

    // ---- GEMM1: h = relu(xb @ enc_w1 + b1) ----
    mfma_gemm<0><<<dim3((512 / BN) * (BATCH / BM)), NTHR, 0, stream>>>(
        xb, w1b, bias1, h, 832, 832, 512, 500, 512 / BN);

    // ---- mid_fused: alpha/beta + sample + GEMM4 ----
    mid_fused<<<dim3(BATCH / 128), NTHR, 0, stream>>>(
        h, wab, biasab, u, dw1b, biasd1, alpha, hdb);

    // ---- GEMM5: recon = sigmoid(hd @ dec_w2 + b) (overwrites xb) ----
    mfma_gemm<2><<<dim3((896 / BN) * (BATCH / BM)), NTHR, 0, stream>>>(
        hdb, dw2b, biasd2, recon, 512, 512, 784, 784, 896 / BN);
}

// Round 18
// 150.602 us; speedup vs baseline: 1.0033x; 1.0033x over previous
//
#include <hip/hip_runtime.h>
#include <math.h>

// StickBreakingVAE forward, all-bf16 MFMA, 8-wave blocks, XCD swizzle.
// r17: 2-phase LDS double-buffer in mfma_gemm (T3-minimum recipe; one barrier
// per K-tile, loads for t+1 in flight under compute of t). 8-wave blocks keep
// 16 waves/CU at 64KB LDS (r5's 4-wave dbuf failure was occupancy collapse).
// Kernels: prep_cast, GEMM1, mid_fused, GEMM5. B=32768, D=784, H=500, K=50.

typedef __bf16 bf16x8 __attribute__((ext_vector_type(8)));
typedef float f32x4 __attribute__((ext_vector_type(4)));

#define BATCH 32768
#define BM 128
#define BN 128
#define BK 64
#define NTHR 512

__device__ __forceinline__ unsigned short bf16_bits(float f) {
    __bf16 b = (__bf16)f;
    return __builtin_bit_cast(unsigned short, b);
}

__device__ __forceinline__ float f32_from_bf16(unsigned short s) {
    unsigned int ui = ((unsigned int)s) << 16;
    return __builtin_bit_cast(float, ui);
}

__device__ __forceinline__ void gll16(const void* src, void* ldsdst) {
    __builtin_amdgcn_global_load_lds(
        (const __attribute__((address_space(1))) unsigned int*)src,
        (__attribute__((address_space(3))) unsigned int*)ldsdst,
        16, 0, 0);
}

// chunked bijective XCD swizzle (T1, m204)
__device__ __forceinline__ int xcd_swz(int orig, int nwg) {
    int q = nwg >> 3, r8 = nwg & 7;
    int xcd = orig & 7;
    int chunkbase = (xcd < r8) ? xcd * (q + 1) : r8 * (q + 1) + (xcd - r8) * q;
    return chunkbase + (orig >> 3);
}

// MODE 0: relu -> bf16 C [ldc]; MODE 2: sigmoid -> f32 C [B,Nreal] masked.
template<int MODE>
__global__ __launch_bounds__(NTHR, 4) void mfma_gemm(
    const unsigned short* __restrict__ A,   // [M][lda] bf16 (zero-padded)
    const unsigned short* __restrict__ Bt,  // [Npad][Kpad] bf16 (zero-padded)
    const float* __restrict__ bias,         // [Npad]
    void* __restrict__ Cv,
    int Kpad, int lda, int ldc, int Nreal, int nbx)
{
    __shared__ unsigned short As[2][BM * BK];   // double-buffered, 64KB total
    __shared__ unsigned short Bs[2][BN * BK];

    const int wgid = xcd_swz(blockIdx.x, gridDim.x);
    const int bn = wgid % nbx;
    const size_t block_m = (size_t)(wgid / nbx) * BM;
    const int block_n = bn * BN;

    const int tid = threadIdx.x;
    const int l = tid & 63;
    const int wid = tid >> 6;
    const int wr = wid >> 2, wc = wid & 3;   // wave tile 64x32
    const int lr = l & 15;
    const int kh = l >> 4;

    f32x4 acc[4][2] = {};

    auto stage = [&](int k0, int buf) {
        #pragma unroll
        for (int i = 0; i < 2; ++i) {
            int chunk = wid * 2 + i;          // 16 chunks x 64 granules(16B)
            int gid = chunk * 64 + l;
            int r = gid >> 3;                 // tile row 0..127
            int kgs = (gid & 7) ^ (r & 7);    // pre-swizzled source granule
            gll16(Bt + (size_t)(block_n + r) * Kpad + k0 + kgs * 8,
                  &Bs[buf][chunk * 512]);
            gll16(A + (block_m + r) * (size_t)lda + k0 + kgs * 8,
                  &As[buf][chunk * 512]);
        }
    };

    auto compute = [&](int buf) {
        #pragma unroll
        for (int s = 0; s < 2; ++s) {
            bf16x8 af[4], bf[2];
            #pragma unroll
            for (int mi = 0; mi < 4; ++mi) {
                int row = wr * 64 + mi * 16 + lr;
                int g = (s * 4 + kh) ^ (row & 7);
                af[mi] = *(const bf16x8*)(&As[buf][row * 64 + g * 8]);
            }
            #pragma unroll
            for (int ni = 0; ni < 2; ++ni) {
                int row = wc * 32 + ni * 16 + lr;
                int g = (s * 4 + kh) ^ (row & 7);
                bf[ni] = *(const bf16x8*)(&Bs[buf][row * 64 + g * 8]);
            }
            #pragma unroll
            for (int mi = 0; mi < 4; ++mi)
                #pragma unroll
                for (int ni = 0; ni < 2; ++ni)
                    acc[mi][ni] = __builtin_amdgcn_mfma_f32_16x16x32_bf16(
                        af[mi], bf[ni], acc[mi][ni], 0, 0, 0);
        }
    };

    const int nt = Kpad / BK;
    stage(0, 0);
    __syncthreads();                          // tile 0 landed
    for (int t = 0; t < nt; ++t) {
        if (t + 1 < nt) stage((t + 1) * BK, (t + 1) & 1);   // prefetch next
        compute(t & 1);
        __syncthreads();   // my glls drained + all waves done reading buf t&1
    }

    const int rg = (l >> 4) * 4;
    #pragma unroll
    for (int mi = 0; mi < 4; ++mi) {
        #pragma unroll
        for (int ni = 0; ni < 2; ++ni) {
            int gn = block_n + wc * 32 + ni * 16 + lr;
            float bs = bias[gn];
            #pragma unroll
            for (int j = 0; j < 4; ++j) {
                long gm = block_m + wr * 64 + mi * 16 + rg + j;
                float z = acc[mi][ni][j] + bs;
                if (MODE == 0) {
                    z = fmaxf(z, 0.f);
                    ((unsigned short*)Cv)[gm * ldc + gn] = bf16_bits(z);
                } else {
                    if (gn < Nreal) {
                        z = __fdividef(1.f, 1.f + __expf(-z));
                        ((float*)Cv)[gm * Nreal + gn] = z;
                    }
                }
            }
        }
    }
}

// Fused GEMM2/3 + softplus + sample + GEMM4. Grid 256 x 512thr, 80KB LDS.
__global__ __launch_bounds__(NTHR, 2) void mid_fused(
    const unsigned short* __restrict__ h,      // [B][512] bf16
    const unsigned short* __restrict__ wab,    // [128][512] bf16
    const float* __restrict__ biasab,          // [128]
    const float* __restrict__ u,               // [B][50] f32
    const unsigned short* __restrict__ dw1b,   // [512][64] bf16
    const float* __restrict__ biasd1,          // [512]
    float* __restrict__ outAB,                 // alpha base (d_out + B*784)
    unsigned short* __restrict__ hdb)          // [B][512] bf16 (aliases h)
{
    __shared__ __align__(16) unsigned char smem[81920];   // 80 KB -> 2 blocks/CU
    unsigned short* abh = (unsigned short*)smem;          // [2][128][64] bf16, 32KB
    unsigned short* Pi  = (unsigned short*)(smem + 32768);       // [128][64], 16KB
    unsigned short* Wd  = (unsigned short*)(smem + 49152);       // [2][128][64], 32KB
    unsigned short* As  = (unsigned short*)(smem + 49152);       // P1 alias of Wd
    unsigned short* Bs  = (unsigned short*)(smem + 65536);

    const int tid = threadIdx.x;
    const int l = tid & 63;
    const int wid = tid >> 6;
    const int wr = wid >> 2, wc = wid & 3;
    const int lr = l & 15;
    const int kh = l >> 4;
    const int rg = (l >> 4) * 4;

    const int wgid = xcd_swz(blockIdx.x, gridDim.x);
    const size_t block_m = (size_t)wgid * 128;

    // ---- P1: alpha/beta pre-act = h @ wab, K=512 ----
    {
        f32x4 acc[4][2] = {};
        for (int k0 = 0; k0 < 512; k0 += BK) {
            #pragma unroll
            for (int i = 0; i < 2; ++i) {
                int chunk = wid * 2 + i;
                int gid = chunk * 64 + l;
                int r = gid >> 3;
                int kgs = (gid & 7) ^ (r & 7);
                gll16(wab + (size_t)r * 512 + k0 + kgs * 8, Bs + chunk * 512);
            }
            #pragma unroll
            for (int i = 0; i < 2; ++i) {
                int chunk = wid * 2 + i;
                int gid = chunk * 64 + l;
                int r = gid >> 3;
                int kgs = (gid & 7) ^ (r & 7);
                gll16(h + (block_m + r) * 512 + k0 + kgs * 8, As + chunk * 512);
            }
            __syncthreads();
            #pragma unroll
            for (int s = 0; s < 2; ++s) {
                bf16x8 af[4], bf[2];
                #pragma unroll
                for (int mi = 0; mi < 4; ++mi) {
                    int row = wr * 64 + mi * 16 + lr;
                    int g = (s * 4 + kh) ^ (row & 7);
                    af[mi] = *(const bf16x8*)(As + row * 64 + g * 8);
                }
                #pragma unroll
                for (int ni = 0; ni < 2; ++ni) {
                    int row = wc * 32 + ni * 16 + lr;
                    int g = (s * 4 + kh) ^ (row & 7);
                    bf[ni] = *(const bf16x8*)(Bs + row * 64 + g * 8);
                }
                #pragma unroll
                for (int mi = 0; mi < 4; ++mi)
                    #pragma unroll
                    for (int ni = 0; ni < 2; ++ni)
                        acc[mi][ni] = __builtin_amdgcn_mfma_f32_16x16x32_bf16(
                            af[mi], bf[ni], acc[mi][ni], 0, 0, 0);
            }
            __syncthreads();   // last iter: As/Bs reads done -> Wd region reusable
        }

        // ---- stage dec_w1 tile 0 early (lands during P2/P3) ----
        #pragma unroll
        for (int i = 0; i < 2; ++i) {
            int chunk = wid * 2 + i;
            int gid = chunk * 64 + l;
            int r = gid >> 3;
            int kgs = (gid & 7) ^ (r & 7);
            gll16(dw1b + (size_t)r * 64 + kgs * 8, Wd + chunk * 512);
        }

        // ---- P2: softplus -> d_out (f32 exact) + LDS ab (bf16) ----
        #pragma unroll
        for (int mi = 0; mi < 4; ++mi) {
            #pragma unroll
            for (int ni = 0; ni < 2; ++ni) {
                int gn = wc * 32 + ni * 16 + lr;       // 0..127
                float bs = biasab[gn];
                #pragma unroll
                for (int j = 0; j < 4; ++j) {
                    int lm = wr * 64 + mi * 16 + rg + j;
                    long gm = block_m + lm;
                    float z = acc[mi][ni][j] + bs;
                    z = (z > 0.f) ? z + __logf(1.f + __expf(-z))
                                  : __logf(1.f + __expf(z));
                    if (gn < 50) {
                        outAB[gm * 50 + gn] = z;
                        abh[lm * 64 + gn] = bf16_bits(z);               // alpha
                    } else if (gn < 100) {
                        outAB[(size_t)BATCH * 50 + gm * 50 + (gn - 50)] = z;
                        abh[8192 + lm * 64 + (gn - 50)] = bf16_bits(z); // beta
                    }
                }
            }
        }
    }

    // ---- P3: sample. u hoisted to regs BEFORE barrier; a,b from LDS bf16 ----
    float ur[16];
    #pragma unroll
    for (int rr = 0; rr < 16; ++rr) {
        size_t grow = block_m + wid * 16 + rr;
        ur[rr] = (l < 50) ? u[grow * 50 + l] : 0.5f;
    }
    __syncthreads();   // abh visible (drains vmcnt too; Wd tile0 landed)

    #pragma unroll
    for (int rr = 0; rr < 16; ++rr) {
        int row = wid * 16 + rr;
        float v = 0.f, w = 1.f;
        if (l < 50) {
            float a = f32_from_bf16(abh[row * 64 + l]);
            float b = f32_from_bf16(abh[8192 + row * 64 + l]);
            float t = exp2f(__fdividef(log2f(ur[rr]), b));      // u^(1/beta)
            v = exp2f(__fdividef(log2f(1.f - t), a));           // (1-t)^(1/alpha)
            w = 1.f - v;
        }
        float p = w;
        #pragma unroll
        for (int off = 1; off < 64; off <<= 1) {
            float t2 = __shfl_up(p, off, 64);
            if (l >= off) p *= t2;
        }
        float ex = __shfl_up(p, 1, 64);
        if (l == 0) ex = 1.f;
        float pi = (l < 50) ? v * ex : 0.f;
        Pi[row * 64 + (((l >> 3) ^ (row & 7)) << 3) + (l & 7)] = bf16_bits(pi);
    }
    __syncthreads();   // Pi ready

    // ---- P4: hd = relu(pi @ dec_w1 + b), 4 n-tiles, Wd dbuf ----
    for (int j = 0; j < 4; ++j) {
        if (j < 3) {
            int buf = (j + 1) & 1;
            #pragma unroll
            for (int i = 0; i < 2; ++i) {
                int chunk = wid * 2 + i;
                int gid = chunk * 64 + l;
                int r = gid >> 3;
                int kgs = (gid & 7) ^ (r & 7);
                gll16(dw1b + (size_t)((j + 1) * 128 + r) * 64 + kgs * 8,
                      Wd + buf * 8192 + chunk * 512);
            }
        }
        f32x4 acc[4][2] = {};
        const unsigned short* W = Wd + (j & 1) * 8192;
        #pragma unroll
        for (int s = 0; s < 2; ++s) {
            bf16x8 af[4], bf[2];
            #pragma unroll
            for (int mi = 0; mi < 4; ++mi) {
                int row = wr * 64 + mi * 16 + lr;
                int g = (s * 4 + kh) ^ (row & 7);
                af[mi] = *(const bf16x8*)(Pi + row * 64 + g * 8);
            }
            #pragma unroll
            for (int ni = 0; ni < 2; ++ni) {
                int row = wc * 32 + ni * 16 + lr;
                int g = (s * 4 + kh) ^ (row & 7);
                bf[ni] = *(const bf16x8*)(W + row * 64 + g * 8);
            }
            #pragma unroll
            for (int mi = 0; mi < 4; ++mi)
                #pragma unroll
                for (int ni = 0; ni < 2; ++ni)
                    acc[mi][ni] = __builtin_amdgcn_mfma_f32_16x16x32_bf16(
                        af[mi], bf[ni], acc[mi][ni], 0, 0, 0);
        }
        #pragma unroll
        for (int mi = 0; mi < 4; ++mi) {
            #pragma unroll
            for (int ni = 0; ni < 2; ++ni) {
                int gn = j * 128 + wc * 32 + ni * 16 + lr;
                float bs = biasd1[gn];
                #pragma unroll
                for (int jj = 0; jj < 4; ++jj) {
                    long gm = block_m + wr * 64 + mi * 16 + rg + jj;
                    float z = fmaxf(acc[mi][ni][jj] + bs, 0.f);
                    hdb[gm * 512 + gn] = bf16_bits(z);
                }
            }
        }
        __syncthreads();   // Wd[j&1] reads done + next tile landed
    }
}

// Merged weight preps + cast_x. blockIdx ranges:
//  [0,1664): w1b  [1664,1920): wab  [1920,2048): dw1b  [2048,3840): dw2b
//  [3840, 3840+13312): cast_x granule pass
__global__ __launch_bounds__(256) void prep_cast(
    const float* __restrict__ x, unsigned short* __restrict__ xb,
    const float* __restrict__ enc_w1, const float* __restrict__ enc_b1,
    const float* __restrict__ Wa, const float* __restrict__ ba,
    const float* __restrict__ Wb, const float* __restrict__ bb,
    const float* __restrict__ dec_w1, const float* __restrict__ dec_b1,
    const float* __restrict__ dec_w2, const float* __restrict__ dec_b2,
    unsigned short* __restrict__ w1b, float* __restrict__ bias1,
    unsigned short* __restrict__ wab, float* __restrict__ biasab,
    unsigned short* __restrict__ dw1b, float* __restrict__ biasd1,
    unsigned short* __restrict__ dw2b, float* __restrict__ biasd2)
{
    int bid = blockIdx.x;
    int t = threadIdx.x;
    if (bid >= 3840) {                   // cast_x: x f32 -> xb bf16 [B][832]
        int gid = (bid - 3840) * 256 + t;
        int r = gid / 104;
        int c = gid - r * 104;
        union { __bf16 b[8]; uint4 u4; } pk;
        if (c < 98) {
            const float4* p = (const float4*)(x + (size_t)r * 784 + c * 8);
            float4 f0 = p[0], f1 = p[1];
            pk.b[0] = (__bf16)f0.x; pk.b[1] = (__bf16)f0.y;
            pk.b[2] = (__bf16)f0.z; pk.b[3] = (__bf16)f0.w;
            pk.b[4] = (__bf16)f1.x; pk.b[5] = (__bf16)f1.y;
            pk.b[6] = (__bf16)f1.z; pk.b[7] = (__bf16)f1.w;
        } else {
            pk.u4 = make_uint4(0, 0, 0, 0);
        }
        *(uint4*)(xb + (size_t)r * 832 + c * 8) = pk.u4;
    } else if (bid < 1664) {             // w1b
        int idx = bid * 256 + t;
        int n = idx / 832, k = idx - n * 832;
        float v = (n < 500 && k < 784) ? enc_w1[(size_t)k * 500 + n] : 0.f;
        w1b[idx] = bf16_bits(v);
        if (k == 0) bias1[n] = (n < 500) ? enc_b1[n] : 0.f;
    } else if (bid < 1920) {             // wab
        int idx = (bid - 1664) * 256 + t;
        int n = idx >> 9, k = idx & 511;
        float v = 0.f;
        if (k < 500) {
            if (n < 50)       v = Wa[(size_t)k * 50 + n];
            else if (n < 100) v = Wb[(size_t)k * 50 + (n - 50)];
        }
        wab[idx] = bf16_bits(v);
        if (k == 0) biasab[n] = (n < 50) ? ba[n] : ((n < 100) ? bb[n - 50] : 0.f);
    } else if (bid < 2048) {             // dw1b
        int idx = (bid - 1920) * 256 + t;
        int n = idx >> 6, k = idx & 63;
        float v = (n < 500 && k < 50) ? dec_w1[(size_t)k * 500 + n] : 0.f;
        dw1b[idx] = bf16_bits(v);
        if (k == 0) biasd1[n] = (n < 500) ? dec_b1[n] : 0.f;
    } else {                             // dw2b
        int idx = (bid - 2048) * 256 + t;
        int n = idx >> 9, k = idx & 511;
        float v = (n < 784 && k < 500) ? dec_w2[(size_t)k * 784 + n] : 0.f;
        dw2b[idx] = bf16_bits(v);
        if (k == 0) biasd2[n] = (n < 784) ? dec_b2[n] : 0.f;
    }
}

extern "C" void kernel_launch(void* const* d_in, const int* in_sizes, int n_in,
                              void* d_out, int out_size, void* d_ws, size_t ws_size,
                              hipStream_t stream) {
    const float* x       = (const float*)d_in[0];
    const float* u       = (const float*)d_in[1];
    const float* enc_w1  = (const float*)d_in[2];
    const float* enc_b1  = (const float*)d_in[3];
    const float* w_alpha = (const float*)d_in[4];
    const float* b_alpha = (const float*)d_in[5];
    const float* w_beta  = (const float*)d_in[6];
    const float* b_beta  = (const float*)d_in[7];
    const float* dec_w1  = (const float*)d_in[8];
    const float* dec_b1  = (const float*)d_in[9];
    const float* dec_w2  = (const float*)d_in[10];
    const float* dec_b2  = (const float*)d_in[11];

    const int D = 784;

    float* out   = (float*)d_out;
    float* recon = out;                              // [B,784] f32
    float* alpha = out + (size_t)BATCH * D;          // [B,50]; beta at +B*50

    unsigned short* xb = (unsigned short*)d_out;     // [B][832] bf16, dead til GEMM5

    char* ws = (char*)d_ws;
    unsigned short* w1b  = (unsigned short*)(ws);             // 512*832*2
    unsigned short* wab  = (unsigned short*)(ws + 851968);    // 128*512*2
    unsigned short* dw1b = (unsigned short*)(ws + 983040);    // 512*64*2
    unsigned short* dw2b = (unsigned short*)(ws + 1048576);   // 896*512*2
    float* bias1  = (float*)(ws + 1966080);
    float* biasab = (float*)(ws + 1968128);
    float* biasd1 = (float*)(ws + 1970688);
    float* biasd2 = (float*)(ws + 1972736);
    unsigned short* h    = (unsigned short*)(ws + 2097152);   // [B][512] bf16
    unsigned short* hdb  = h;                                  // per-block phase-safe alias

    // ---- prep + cast (one launch) ----
    prep_cast<<<dim3(3840 + BATCH * 104 / 256), 256, 0, stream>>>(
        x, xb, enc_w1, enc_b1, w_alpha, b_alpha, w_beta, b_beta,
        dec_w1, dec_b1, dec_w2, dec_b2,
        w1b, bias1, wab, biasab, dw1b, biasd1, dw2b, biasd2);

    // ---- GEMM1: h = relu(xb @ enc_w1 + b1) ----
    mfma_gemm<0><<<dim3((512 / BN) * (BATCH / BM)), NTHR, 0, stream>>>(
        xb, w1b, bias1, h, 832, 832, 512, 500, 512 / BN);

    // ---- mid_fused: alpha/beta + sample + GEMM4 ----
    mid_fused<<<dim3(BATCH / 128), NTHR, 0, stream>>>(
        h, wab, biasab, u, dw1b, biasd1, alpha, hdb);

    // ---- GEMM5: recon = sigmoid(hd @ dec_w2 + b) (overwrites xb) ----
    mfma_gemm<2><<<dim3((896 / BN) * (BATCH / BM)), NTHR, 0, stream>>>(
        hdb, dw2b, biasd2, recon, 512, 512, 784, 784, 896 / BN);
}

// Round 19
// 145.127 us; speedup vs baseline: 1.0412x; 1.0377x over previous
//
#include <hip/hip_runtime.h>
#include <math.h>

// StickBreakingVAE forward, all-bf16 MFMA, 8-wave blocks, XCD swizzle.
// r19: REVERT to r16 structure (single-buffered 2-barrier GEMM — dbuf regressed
// in r5/r17 at two occupancy points; lever retired) + nontemporal stores for
// write-once outputs (recon, alpha/beta) to keep L2 free for weight/act reuse.
// Kernels: prep_cast, GEMM1, mid_fused, GEMM5. B=32768, D=784, H=500, K=50.

typedef __bf16 bf16x8 __attribute__((ext_vector_type(8)));
typedef float f32x4 __attribute__((ext_vector_type(4)));

#define BATCH 32768
#define BM 128
#define BN 128
#define BK 64
#define NTHR 512

__device__ __forceinline__ unsigned short bf16_bits(float f) {
    __bf16 b = (__bf16)f;
    return __builtin_bit_cast(unsigned short, b);
}

__device__ __forceinline__ float f32_from_bf16(unsigned short s) {
    unsigned int ui = ((unsigned int)s) << 16;
    return __builtin_bit_cast(float, ui);
}

__device__ __forceinline__ void gll16(const void* src, void* ldsdst) {
    __builtin_amdgcn_global_load_lds(
        (const __attribute__((address_space(1))) unsigned int*)src,
        (__attribute__((address_space(3))) unsigned int*)ldsdst,
        16, 0, 0);
}

// chunked bijective XCD swizzle (T1, m204)
__device__ __forceinline__ int xcd_swz(int orig, int nwg) {
    int q = nwg >> 3, r8 = nwg & 7;
    int xcd = orig & 7;
    int chunkbase = (xcd < r8) ? xcd * (q + 1) : r8 * (q + 1) + (xcd - r8) * q;
    return chunkbase + (orig >> 3);
}

// MODE 0: relu -> bf16 C [ldc]; MODE 2: sigmoid -> f32 C [B,Nreal] masked (nt).
template<int MODE>
__global__ __launch_bounds__(NTHR, 4) void mfma_gemm(
    const unsigned short* __restrict__ A,   // [M][lda] bf16 (zero-padded)
    const unsigned short* __restrict__ Bt,  // [Npad][Kpad] bf16 (zero-padded)
    const float* __restrict__ bias,         // [Npad]
    void* __restrict__ Cv,
    int Kpad, int lda, int ldc, int Nreal, int nbx)
{
    __shared__ unsigned short As[BM * BK];   // linear row*64 + swizzled-granule*8
    __shared__ unsigned short Bs[BN * BK];

    const int wgid = xcd_swz(blockIdx.x, gridDim.x);
    const int bn = wgid % nbx;               // n fastest -> A-panel L2 reuse
    const size_t block_m = (size_t)(wgid / nbx) * BM;
    const int block_n = bn * BN;

    const int tid = threadIdx.x;
    const int l = tid & 63;
    const int wid = tid >> 6;
    const int wr = wid >> 2, wc = wid & 3;   // wave tile 64x32
    const int lr = l & 15;
    const int kh = l >> 4;

    f32x4 acc[4][2] = {};

    for (int k0 = 0; k0 < Kpad; k0 += BK) {
        #pragma unroll
        for (int i = 0; i < 2; ++i) {
            int chunk = wid * 2 + i;          // 16 chunks x 64 granules(16B)
            int gid = chunk * 64 + l;
            int r = gid >> 3;                 // tile row 0..127
            int kgs = (gid & 7) ^ (r & 7);    // pre-swizzled source granule
            gll16(Bt + (size_t)(block_n + r) * Kpad + k0 + kgs * 8, Bs + chunk * 512);
        }
        #pragma unroll
        for (int i = 0; i < 2; ++i) {
            int chunk = wid * 2 + i;
            int gid = chunk * 64 + l;
            int r = gid >> 3;
            int kgs = (gid & 7) ^ (r & 7);
            gll16(A + (block_m + r) * (size_t)lda + k0 + kgs * 8, As + chunk * 512);
        }
        __syncthreads();
        #pragma unroll
        for (int s = 0; s < 2; ++s) {
            bf16x8 af[4], bf[2];
            #pragma unroll
            for (int mi = 0; mi < 4; ++mi) {
                int row = wr * 64 + mi * 16 + lr;
                int g = (s * 4 + kh) ^ (row & 7);
                af[mi] = *(const bf16x8*)(As + row * 64 + g * 8);
            }
            #pragma unroll
            for (int ni = 0; ni < 2; ++ni) {
                int row = wc * 32 + ni * 16 + lr;
                int g = (s * 4 + kh) ^ (row & 7);
                bf[ni] = *(const bf16x8*)(Bs + row * 64 + g * 8);
            }
            #pragma unroll
            for (int mi = 0; mi < 4; ++mi)
                #pragma unroll
                for (int ni = 0; ni < 2; ++ni)
                    acc[mi][ni] = __builtin_amdgcn_mfma_f32_16x16x32_bf16(
                        af[mi], bf[ni], acc[mi][ni], 0, 0, 0);
        }
        __syncthreads();
    }

    const int rg = (l >> 4) * 4;
    #pragma unroll
    for (int mi = 0; mi < 4; ++mi) {
        #pragma unroll
        for (int ni = 0; ni < 2; ++ni) {
            int gn = block_n + wc * 32 + ni * 16 + lr;
            float bs = bias[gn];
            #pragma unroll
            for (int j = 0; j < 4; ++j) {
                long gm = block_m + wr * 64 + mi * 16 + rg + j;
                float z = acc[mi][ni][j] + bs;
                if (MODE == 0) {
                    z = fmaxf(z, 0.f);
                    ((unsigned short*)Cv)[gm * ldc + gn] = bf16_bits(z);
                } else {
                    if (gn < Nreal) {
                        z = __fdividef(1.f, 1.f + __expf(-z));
                        // recon is write-once: bypass L2
                        __builtin_nontemporal_store(z, &((float*)Cv)[gm * Nreal + gn]);
                    }
                }
            }
        }
    }
}

// Fused GEMM2/3 + softplus + sample + GEMM4. Grid 256 x 512thr, 80KB LDS.
__global__ __launch_bounds__(NTHR, 2) void mid_fused(
    const unsigned short* __restrict__ h,      // [B][512] bf16
    const unsigned short* __restrict__ wab,    // [128][512] bf16
    const float* __restrict__ biasab,          // [128]
    const float* __restrict__ u,               // [B][50] f32
    const unsigned short* __restrict__ dw1b,   // [512][64] bf16
    const float* __restrict__ biasd1,          // [512]
    float* __restrict__ outAB,                 // alpha base (d_out + B*784)
    unsigned short* __restrict__ hdb)          // [B][512] bf16 (aliases h)
{
    __shared__ __align__(16) unsigned char smem[81920];   // 80 KB -> 2 blocks/CU
    unsigned short* abh = (unsigned short*)smem;          // [2][128][64] bf16, 32KB
    unsigned short* Pi  = (unsigned short*)(smem + 32768);       // [128][64], 16KB
    unsigned short* Wd  = (unsigned short*)(smem + 49152);       // [2][128][64], 32KB
    unsigned short* As  = (unsigned short*)(smem + 49152);       // P1 alias of Wd
    unsigned short* Bs  = (unsigned short*)(smem + 65536);

    const int tid = threadIdx.x;
    const int l = tid & 63;
    const int wid = tid >> 6;
    const int wr = wid >> 2, wc = wid & 3;
    const int lr = l & 15;
    const int kh = l >> 4;
    const int rg = (l >> 4) * 4;

    const int wgid = xcd_swz(blockIdx.x, gridDim.x);
    const size_t block_m = (size_t)wgid * 128;

    // ---- P1: alpha/beta pre-act = h @ wab, K=512 ----
    {
        f32x4 acc[4][2] = {};
        for (int k0 = 0; k0 < 512; k0 += BK) {
            #pragma unroll
            for (int i = 0; i < 2; ++i) {
                int chunk = wid * 2 + i;
                int gid = chunk * 64 + l;
                int r = gid >> 3;
                int kgs = (gid & 7) ^ (r & 7);
                gll16(wab + (size_t)r * 512 + k0 + kgs * 8, Bs + chunk * 512);
            }
            #pragma unroll
            for (int i = 0; i < 2; ++i) {
                int chunk = wid * 2 + i;
                int gid = chunk * 64 + l;
                int r = gid >> 3;
                int kgs = (gid & 7) ^ (r & 7);
                gll16(h + (block_m + r) * 512 + k0 + kgs * 8, As + chunk * 512);
            }
            __syncthreads();
            #pragma unroll
            for (int s = 0; s < 2; ++s) {
                bf16x8 af[4], bf[2];
                #pragma unroll
                for (int mi = 0; mi < 4; ++mi) {
                    int row = wr * 64 + mi * 16 + lr;
                    int g = (s * 4 + kh) ^ (row & 7);
                    af[mi] = *(const bf16x8*)(As + row * 64 + g * 8);
                }
                #pragma unroll
                for (int ni = 0; ni < 2; ++ni) {
                    int row = wc * 32 + ni * 16 + lr;
                    int g = (s * 4 + kh) ^ (row & 7);
                    bf[ni] = *(const bf16x8*)(Bs + row * 64 + g * 8);
                }
                #pragma unroll
                for (int mi = 0; mi < 4; ++mi)
                    #pragma unroll
                    for (int ni = 0; ni < 2; ++ni)
                        acc[mi][ni] = __builtin_amdgcn_mfma_f32_16x16x32_bf16(
                            af[mi], bf[ni], acc[mi][ni], 0, 0, 0);
            }
            __syncthreads();   // last iter: As/Bs reads done -> Wd region reusable
        }

        // ---- stage dec_w1 tile 0 early (lands during P2/P3) ----
        #pragma unroll
        for (int i = 0; i < 2; ++i) {
            int chunk = wid * 2 + i;
            int gid = chunk * 64 + l;
            int r = gid >> 3;
            int kgs = (gid & 7) ^ (r & 7);
            gll16(dw1b + (size_t)r * 64 + kgs * 8, Wd + chunk * 512);
        }

        // ---- P2: softplus -> d_out (f32 exact, nt write-once) + LDS ab (bf16) ----
        #pragma unroll
        for (int mi = 0; mi < 4; ++mi) {
            #pragma unroll
            for (int ni = 0; ni < 2; ++ni) {
                int gn = wc * 32 + ni * 16 + lr;       // 0..127
                float bs = biasab[gn];
                #pragma unroll
                for (int j = 0; j < 4; ++j) {
                    int lm = wr * 64 + mi * 16 + rg + j;
                    long gm = block_m + lm;
                    float z = acc[mi][ni][j] + bs;
                    z = (z > 0.f) ? z + __logf(1.f + __expf(-z))
                                  : __logf(1.f + __expf(z));
                    if (gn < 50) {
                        __builtin_nontemporal_store(z, &outAB[gm * 50 + gn]);
                        abh[lm * 64 + gn] = bf16_bits(z);               // alpha
                    } else if (gn < 100) {
                        __builtin_nontemporal_store(
                            z, &outAB[(size_t)BATCH * 50 + gm * 50 + (gn - 50)]);
                        abh[8192 + lm * 64 + (gn - 50)] = bf16_bits(z); // beta
                    }
                }
            }
        }
    }

    // ---- P3: sample. u hoisted to regs BEFORE barrier; a,b from LDS bf16 ----
    float ur[16];
    #pragma unroll
    for (int rr = 0; rr < 16; ++rr) {
        size_t grow = block_m + wid * 16 + rr;
        ur[rr] = (l < 50) ? u[grow * 50 + l] : 0.5f;
    }
    __syncthreads();   // abh visible (drains vmcnt too; Wd tile0 landed)

    #pragma unroll
    for (int rr = 0; rr < 16; ++rr) {
        int row = wid * 16 + rr;
        float v = 0.f, w = 1.f;
        if (l < 50) {
            float a = f32_from_bf16(abh[row * 64 + l]);
            float b = f32_from_bf16(abh[8192 + row * 64 + l]);
            float t = exp2f(__fdividef(log2f(ur[rr]), b));      // u^(1/beta)
            v = exp2f(__fdividef(log2f(1.f - t), a));           // (1-t)^(1/alpha)
            w = 1.f - v;
        }
        float p = w;
        #pragma unroll
        for (int off = 1; off < 64; off <<= 1) {
            float t2 = __shfl_up(p, off, 64);
            if (l >= off) p *= t2;
        }
        float ex = __shfl_up(p, 1, 64);
        if (l == 0) ex = 1.f;
        float pi = (l < 50) ? v * ex : 0.f;
        Pi[row * 64 + (((l >> 3) ^ (row & 7)) << 3) + (l & 7)] = bf16_bits(pi);
    }
    __syncthreads();   // Pi ready

    // ---- P4: hd = relu(pi @ dec_w1 + b), 4 n-tiles, Wd dbuf ----
    for (int j = 0; j < 4; ++j) {
        if (j < 3) {
            int buf = (j + 1) & 1;
            #pragma unroll
            for (int i = 0; i < 2; ++i) {
                int chunk = wid * 2 + i;
                int gid = chunk * 64 + l;
                int r = gid >> 3;
                int kgs = (gid & 7) ^ (r & 7);
                gll16(dw1b + (size_t)((j + 1) * 128 + r) * 64 + kgs * 8,
                      Wd + buf * 8192 + chunk * 512);
            }
        }
        f32x4 acc[4][2] = {};
        const unsigned short* W = Wd + (j & 1) * 8192;
        #pragma unroll
        for (int s = 0; s < 2; ++s) {
            bf16x8 af[4], bf[2];
            #pragma unroll
            for (int mi = 0; mi < 4; ++mi) {
                int row = wr * 64 + mi * 16 + lr;
                int g = (s * 4 + kh) ^ (row & 7);
                af[mi] = *(const bf16x8*)(Pi + row * 64 + g * 8);
            }
            #pragma unroll
            for (int ni = 0; ni < 2; ++ni) {
                int row = wc * 32 + ni * 16 + lr;
                int g = (s * 4 + kh) ^ (row & 7);
                bf[ni] = *(const bf16x8*)(W + row * 64 + g * 8);
            }
            #pragma unroll
            for (int mi = 0; mi < 4; ++mi)
                #pragma unroll
                for (int ni = 0; ni < 2; ++ni)
                    acc[mi][ni] = __builtin_amdgcn_mfma_f32_16x16x32_bf16(
                        af[mi], bf[ni], acc[mi][ni], 0, 0, 0);
        }
        #pragma unroll
        for (int mi = 0; mi < 4; ++mi) {
            #pragma unroll
            for (int ni = 0; ni < 2; ++ni) {
                int gn = j * 128 + wc * 32 + ni * 16 + lr;
                float bs = biasd1[gn];
                #pragma unroll
                for (int jj = 0; jj < 4; ++jj) {
                    long gm = block_m + wr * 64 + mi * 16 + rg + jj;
                    float z = fmaxf(acc[mi][ni][jj] + bs, 0.f);
                    hdb[gm * 512 + gn] = bf16_bits(z);
                }
            }
        }
        __syncthreads();   // Wd[j&1] reads done + next tile landed
    }
}

// Merged weight preps + cast_x. blockIdx ranges:
//  [0,1664): w1b  [1664,1920): wab  [1920,2048): dw1b  [2048,3840): dw2b
//  [3840, 3840+13312): cast_x granule pass
__global__ __launch_bounds__(256) void prep_cast(
    const float* __restrict__ x, unsigned short* __restrict__ xb,
    const float* __restrict__ enc_w1, const float* __restrict__ enc_b1,
    const float* __restrict__ Wa, const float* __restrict__ ba,
    const float* __restrict__ Wb, const float* __restrict__ bb,
    const float* __restrict__ dec_w1, const float* __restrict__ dec_b1,
    const float* __restrict__ dec_w2, const float* __restrict__ dec_b2,
    unsigned short* __restrict__ w1b, float* __restrict__ bias1,
    unsigned short* __restrict__ wab, float* __restrict__ biasab,
    unsigned short* __restrict__ dw1b, float* __restrict__ biasd1,
    unsigned short* __restrict__ dw2b, float* __restrict__ biasd2)
{
    int bid = blockIdx.x;
    int t = threadIdx.x;
    if (bid >= 3840) {                   // cast_x: x f32 -> xb bf16 [B][832]
        int gid = (bid - 3840) * 256 + t;
        int r = gid / 104;
        int c = gid - r * 104;
        union { __bf16 b[8]; uint4 u4; } pk;
        if (c < 98) {
            const float4* p = (const float4*)(x + (size_t)r * 784 + c * 8);
            float4 f0 = p[0], f1 = p[1];
            pk.b[0] = (__bf16)f0.x; pk.b[1] = (__bf16)f0.y;
            pk.b[2] = (__bf16)f0.z; pk.b[3] = (__bf16)f0.w;
            pk.b[4] = (__bf16)f1.x; pk.b[5] = (__bf16)f1.y;
            pk.b[6] = (__bf16)f1.z; pk.b[7] = (__bf16)f1.w;
        } else {
            pk.u4 = make_uint4(0, 0, 0, 0);
        }
        *(uint4*)(xb + (size_t)r * 832 + c * 8) = pk.u4;
    } else if (bid < 1664) {             // w1b
        int idx = bid * 256 + t;
        int n = idx / 832, k = idx - n * 832;
        float v = (n < 500 && k < 784) ? enc_w1[(size_t)k * 500 + n] : 0.f;
        w1b[idx] = bf16_bits(v);
        if (k == 0) bias1[n] = (n < 500) ? enc_b1[n] : 0.f;
    } else if (bid < 1920) {             // wab
        int idx = (bid - 1664) * 256 + t;
        int n = idx >> 9, k = idx & 511;
        float v = 0.f;
        if (k < 500) {
            if (n < 50)       v = Wa[(size_t)k * 50 + n];
            else if (n < 100) v = Wb[(size_t)k * 50 + (n - 50)];
        }
        wab[idx] = bf16_bits(v);
        if (k == 0) biasab[n] = (n < 50) ? ba[n] : ((n < 100) ? bb[n - 50] : 0.f);
    } else if (bid < 2048) {             // dw1b
        int idx = (bid - 1920) * 256 + t;
        int n = idx >> 6, k = idx & 63;
        float v = (n < 500 && k < 50) ? dec_w1[(size_t)k * 500 + n] : 0.f;
        dw1b[idx] = bf16_bits(v);
        if (k == 0) biasd1[n] = (n < 500) ? dec_b1[n] : 0.f;
    } else {                             // dw2b
        int idx = (bid - 2048) * 256 + t;
        int n = idx >> 9, k = idx & 511;
        float v = (n < 784 && k < 500) ? dec_w2[(size_t)k * 784 + n] : 0.f;
        dw2b[idx] = bf16_bits(v);
        if (k == 0) biasd2[n] = (n < 784) ? dec_b2[n] : 0.f;
    }
}

extern "C" void kernel_launch(void* const* d_in, const int* in_sizes, int n_in,
                              void* d_out, int out_size, void* d_ws, size_t ws_size,
                              hipStream_t stream) {
    const float* x       = (const float*)d_in[0];
    const float* u       = (const float*)d_in[1];
    const float* enc_w1  = (const float*)d_in[2];
    const float* enc_b1  = (const float*)d_in[3];
    const float* w_alpha = (const float*)d_in[4];
    const float* b_alpha = (const float*)d_in[5];
    const float* w_beta  = (const float*)d_in[6];
    const float* b_beta  = (const float*)d_in[7];
    const float* dec_w1  = (const float*)d_in[8];
    const float* dec_b1  = (const float*)d_in[9];
    const float* dec_w2  = (const float*)d_in[10];
    const float* dec_b2  = (const float*)d_in[11];

    const int D = 784;

    float* out   = (float*)d_out;
    float* recon = out;                              // [B,784] f32
    float* alpha = out + (size_t)BATCH * D;          // [B,50]; beta at +B*50

    unsigned short* xb = (unsigned short*)d_out;     // [B][832] bf16, dead til GEMM5

    char* ws = (char*)d_ws;
    unsigned short* w1b  = (unsigned short*)(ws);             // 512*832*2
    unsigned short* wab  = (unsigned short*)(ws + 851968);    // 128*512*2
    unsigned short* dw1b = (unsigned short*)(ws + 983040);    // 512*64*2
    unsigned short* dw2b = (unsigned short*)(ws + 1048576);   // 896*512*2
    float* bias1  = (float*)(ws + 1966080);
    float* biasab = (float*)(ws + 1968128);
    float* biasd1 = (float*)(ws + 1970688);
    float* biasd2 = (float*)(ws + 1972736);
    unsigned short* h    = (unsigned short*)(ws + 2097152);   // [B][512] bf16
    unsigned short* hdb  = h;                                  // per-block phase-safe alias

    // ---- prep + cast (one launch) ----
    prep_cast<<<dim3(3840 + BATCH * 104 / 256), 256, 0, stream>>>(
        x, xb, enc_w1, enc_b1, w_alpha, b_alpha, w_beta, b_beta,
        dec_w1, dec_b1, dec_w2, dec_b2,
        w1b, bias1, wab, biasab, dw1b, biasd1, dw2b, biasd2);

    // ---- GEMM1: h = relu(xb @ enc_w1 + b1) ----
    mfma_gemm<0><<<dim3((512 / BN) * (BATCH / BM)), NTHR, 0, stream>>>(
        xb, w1b, bias1, h, 832, 832, 512, 500, 512 / BN);

    // ---- mid_fused: alpha/beta + sample + GEMM4 ----
    mid_fused<<<dim3(BATCH / 128), NTHR, 0, stream>>>(
        h, wab, biasab, u, dw1b, biasd1, alpha, hdb);

    // ---- GEMM5: recon = sigmoid(hd @ dec_w2 + b) (overwrites xb) ----
    mfma_gemm<2><<<dim3((896 / BN) * (BATCH / BM)), NTHR, 0, stream>>>(
        hdb, dw2b, biasd2, recon, 512, 512, 784, 784, 896 / BN);
}